// Round 6
// baseline (259.991 us; speedup 1.0000x reference)
//
#include <hip/hip_runtime.h>

#define IN_DIM 8192
#define OUT_DIM 8192
#define BATCH 2048
#define TPB 512                      // 8 waves/block
#define RPB 4                        // rows per block; grid = 512 = 2 blocks/CU
#define NQ (OUT_DIM / 4 / TPB)       // 4 float4-output quads per thread per row
#define NSTG (IN_DIM / 4 / TPB)      // 4 direct-to-LDS 16B loads per thread per row

typedef float fvec4 __attribute__((ext_vector_type(4)));

#define GLOAD_LDS16(gp, lp)                                                        \
    __builtin_amdgcn_global_load_lds(                                              \
        (const __attribute__((address_space(1))) unsigned int*)(gp),               \
        (__attribute__((address_space(3))) unsigned int*)(lp), 16, 0, 0)

#define MEMFENCE() asm volatile("" ::: "memory")

// ---------------------------------------------------------------------------
// Single fused kernel, R3 loop schedule, spill-proof coeff prologue.
//
// R5's failure: the fully-unrolled 16-softmax coeff phase let the scheduler
// hoist all 64 float4 w-loads -> ~250 live VGPRs -> scratch spill (WRITE_SIZE
// 234MB vs 64MB). Fix: sched_barrier(0) after EACH column's softmax pins
// program order, so only one column's 16 w-values are live at a time.
// Persistent state: pi[4] + cA[8] + cB[8] = 80 VGPRs; peak ~115 < 128
// (the 4-waves/SIMD register cliff -> both LDS-resident blocks stay resident).
//
// PROLOGUE: issue DMA(row0->buf0) FIRST (flies under idx-pack + coeff phase),
// pack idx into byte offsets, then 16x {load w row, softmax, 4 coeffs, fence}.
//
// LOOP (issue-early depth-1, counted vmcnt, never drained mid-loop):
//   iter r: bar_A (all waves done READING buf[(r+1)&1])
//           issue DMA(row r+1 -> buf[(r+1)&1])
//           s_waitcnt vmcnt(8)   (steady: retires exactly DMA(r);
//                                 st(r-1) and DMA(r+1) stay in flight)
//           bar_B -> compute row r from buf[r&1], 4x nontemporal float4 stores
//   edges: r==0 and r==RPB-1 -> vmcnt(4).  (At r==0 the coeff-phase w/idx
//   loads are already retired by the compiler's own waits -> FIFO is exactly
//   [DMA(0) x4 | DMA(1) x4] -> vmcnt(4) retires DMA(0).)
// ---------------------------------------------------------------------------
__global__ __launch_bounds__(TPB, 4) void logic_kernel(
    const float* __restrict__ x,
    const float* __restrict__ w,
    const int* __restrict__ idx_a,
    const int* __restrict__ idx_b,
    float* __restrict__ out)
{
    __shared__ float xrow[2][IN_DIM];        // 64 KB -> 2 blocks/CU (LDS-limited)

    const int tid  = threadIdx.x;
    const int row0 = blockIdx.x * RPB;

    // ---- 1. DMA row0 -> buf0 FIRST (overlaps the whole prologue) ----
    {
        const float* xr = x + (size_t)row0 * IN_DIM;
#pragma unroll
        for (int i = 0; i < NSTG; ++i)
            GLOAD_LDS16(xr + 4 * (i * TPB + tid), &xrow[0][4 * (i * TPB + tid)]);
    }
    MEMFENCE();

    // ---- 2. pack indices: pi[q] = (idx_a*4)&0xffff | (idx_b*4)<<18 ----
    int4 pi[NQ];
#pragma unroll
    for (int q = 0; q < NQ; ++q) {
        int j4 = q * TPB + tid;                       // quad of columns 4*j4..4*j4+3
        int4 ia = ((const int4*)idx_a)[j4];
        int4 ib = ((const int4*)idx_b)[j4];
        pi[q].x = ((ia.x << 2) & 0xffff) | (ib.x << 18);
        pi[q].y = ((ia.y << 2) & 0xffff) | (ib.y << 18);
        pi[q].z = ((ia.z << 2) & 0xffff) | (ib.z << 18);
        pi[q].w = ((ia.w << 2) & 0xffff) | (ib.w << 18);
    }
    __builtin_amdgcn_sched_barrier(0);

    // ---- 3. softmax -> affine coeffs, ONE column at a time (fenced) ----
    float4 cA[2 * NQ];       // (c0,ca) pairs: cA[2q+(k>>1)].{xy|zw} = col 4q*TPB+4tid+k
    float4 cB[2 * NQ];       // (cb,cab) pairs, same layout
#pragma unroll
    for (int q = 0; q < NQ; ++q) {
#pragma unroll
        for (int k = 0; k < 4; ++k) {
            int j = 4 * (q * TPB + tid) + k;
            const float4* w4 = (const float4*)(w + (size_t)j * 16);
            float4 q0 = w4[0], q1 = w4[1], q2 = w4[2], q3 = w4[3];
            float wv[16] = { q0.x, q0.y, q0.z, q0.w,
                             q1.x, q1.y, q1.z, q1.w,
                             q2.x, q2.y, q2.z, q2.w,
                             q3.x, q3.y, q3.z, q3.w };
            float m = -1e30f;
#pragma unroll
            for (int t = 0; t < 16; ++t) m = fmaxf(m, wv[t]);
            float s = 0.f;
#pragma unroll
            for (int t = 0; t < 16; ++t) { wv[t] = __expf(wv[t] - m); s += wv[t]; }
            float inv = 1.0f / s;

            float c0  = (wv[8] + wv[9] + wv[10] + wv[11] + wv[12] + wv[13] + wv[14] + wv[15]) * inv;
            float ca  = (wv[2] + wv[3] + wv[6] + wv[7] - wv[8] - wv[9] - wv[12] - wv[13]) * inv;
            float cb  = (wv[4] + wv[5] + wv[6] + wv[7] - wv[8] - wv[9] - wv[10] - wv[11]) * inv;
            float cab = (wv[1] - wv[2] - wv[4] - 2.f * wv[6] - wv[7]
                       + wv[8] + 2.f * wv[9] + wv[11] + wv[13] - wv[14]) * inv;

            if ((k & 1) == 0) { cA[2 * q + (k >> 1)].x = c0; cA[2 * q + (k >> 1)].y = ca;
                                cB[2 * q + (k >> 1)].x = cb; cB[2 * q + (k >> 1)].y = cab; }
            else              { cA[2 * q + (k >> 1)].z = c0; cA[2 * q + (k >> 1)].w = ca;
                                cB[2 * q + (k >> 1)].z = cb; cB[2 * q + (k >> 1)].w = cab; }

            // spill guard: next column's w-loads may NOT hoist above this point
            __builtin_amdgcn_sched_barrier(0);
        }
    }
    MEMFENCE();

#pragma unroll
    for (int r = 0; r < RPB; ++r) {
        // bar_A: every wave finished READING buf[(r+1)&1] (last read in iter r-1)
        __builtin_amdgcn_s_barrier();

        // issue next row's DMA BEFORE waiting on the current row's DMA
        if (r + 1 < RPB) {
            const float* xn = x + (size_t)(row0 + r + 1) * IN_DIM;
#pragma unroll
            for (int i = 0; i < NSTG; ++i)
                GLOAD_LDS16(xn + 4 * (i * TPB + tid), &xrow[(r + 1) & 1][4 * (i * TPB + tid)]);
        }
        MEMFENCE();

        // counted retire of DMA(r) only (never drain to 0 mid-loop)
        if (r == 0 || r + 1 == RPB) asm volatile("s_waitcnt vmcnt(4)" ::: "memory");
        else                        asm volatile("s_waitcnt vmcnt(8)" ::: "memory");
        __builtin_amdgcn_s_barrier();   // bar_B: LDS row r valid for all waves
        MEMFENCE();

        const char* xb = (const char*)xrow[r & 1];
        fvec4* out4 = (fvec4*)(out + (size_t)(row0 + r) * OUT_DIM);

#pragma unroll
        for (int q = 0; q < NQ; ++q) {
            int4 p = pi[q];
            // byte-offset gathers (pi holds idx*4 packed in 16-bit halves)
            float a0 = *(const float*)(xb + (p.x & 0xffff)), b0 = *(const float*)(xb + ((unsigned)p.x >> 16));
            float a1 = *(const float*)(xb + (p.y & 0xffff)), b1 = *(const float*)(xb + ((unsigned)p.y >> 16));
            float a2 = *(const float*)(xb + (p.z & 0xffff)), b2 = *(const float*)(xb + ((unsigned)p.z >> 16));
            float a3 = *(const float*)(xb + (p.w & 0xffff)), b3 = *(const float*)(xb + ((unsigned)p.w >> 16));

            float4 A0 = cA[2 * q], A1 = cA[2 * q + 1];
            float4 B0 = cB[2 * q], B1 = cB[2 * q + 1];

            // o = (c0 + ca*a) + b*(cb + cab*a)   -- 3 FMAs per output
            fvec4 o;
            o.x = fmaf(fmaf(B0.y, a0, B0.x), b0, fmaf(A0.y, a0, A0.x));
            o.y = fmaf(fmaf(B0.w, a1, B0.z), b1, fmaf(A0.w, a1, A0.z));
            o.z = fmaf(fmaf(B1.y, a2, B1.x), b2, fmaf(A1.y, a2, A1.x));
            o.w = fmaf(fmaf(B1.w, a3, B1.z), b3, fmaf(A1.w, a3, A1.z));
            __builtin_nontemporal_store(o, &out4[q * TPB + tid]);
        }
        MEMFENCE();
    }
}

extern "C" void kernel_launch(void* const* d_in, const int* in_sizes, int n_in,
                              void* d_out, int out_size, void* d_ws, size_t ws_size,
                              hipStream_t stream)
{
    const float* x       = (const float*)d_in[0];  // (2048, 8192) fp32
    const float* weights = (const float*)d_in[1];  // (8192, 16)   fp32
    const int*   idx_a   = (const int*)d_in[2];    // (8192,) int32 on device
    const int*   idx_b   = (const int*)d_in[3];    // (8192,) int32 on device
    float* out = (float*)d_out;                    // (2048, 8192) fp32

    logic_kernel<<<BATCH / RPB, TPB, 0, stream>>>(x, weights, idx_a, idx_b, out);
}

// Round 7
// 257.928 us; speedup vs baseline: 1.0080x; 1.0080x over previous
//
#include <hip/hip_runtime.h>

#define IN_DIM 8192
#define OUT_DIM 8192
#define BATCH 2048
#define TPB 512                      // 8 waves/block
#define RPB 4                        // rows per block; grid = 512 = 2 blocks/CU
#define NQ (OUT_DIM / 4 / TPB)       // 4 float4-output quads per thread per row
#define NSTG (IN_DIM / 4 / TPB)      // 4 direct-to-LDS 16B loads per thread per row

typedef float fvec4 __attribute__((ext_vector_type(4)));

#define GLOAD_LDS16(gp, lp)                                                        \
    __builtin_amdgcn_global_load_lds(                                              \
        (const __attribute__((address_space(1))) unsigned int*)(gp),               \
        (__attribute__((address_space(3))) unsigned int*)(lp), 16, 0, 0)

#define MEMFENCE() asm volatile("" ::: "memory")

// ---------------------------------------------------------------------------
// Fused kernel, R3 loop schedule, SROA-safe coeff prologue.
//
// R5/R6 failure mechanism (from counters: VGPR=64 < the 80 persistent regs,
// WRITE_SIZE 307MB): PARTIAL COMPONENT WRITES to the local arrays
// (cA[i].x=..., pi[q].x=...) defeat SROA -> arrays materialized in scratch ->
// every loop access is scratch traffic. NOT a scheduling problem.
// Fix: every store to pi/cA/cB is a WHOLE-OBJECT assignment
// (make_int4/make_float4), as in the never-spilling two-kernel version.
//
// PROLOGUE: issue DMA(row0->buf0) FIRST (flies under the coeff phase);
// pack idx (whole int4 stores); 16x per-column softmax -> coeffs, combined
// pairwise into whole float4 stores; sched_barrier(0) per pair caps the
// transient w-load pressure.
//
// LOOP (R3, unchanged): issue-early depth-1, counted vmcnt, never drained:
//   iter r: bar_A -> issue DMA(r+1) -> vmcnt(8) [edges 4] -> bar_B
//           -> compute row r from buf[r&1], 4x nontemporal float4 stores.
// FIFO at r=0: coeff-phase w-waits already drained the older DMA(0);
// outstanding = DMA(1) x4 -> vmcnt(4). Steady: [DMA(r)x4|st(r-1)x4|DMA(r+1)x4]
// -> vmcnt(8). Last iter: vmcnt(4).
// ---------------------------------------------------------------------------

__device__ __forceinline__ float4 softmax_coeffs(const float* __restrict__ w, int j)
{
    const float4* w4 = (const float4*)(w + (size_t)j * 16);
    float4 q0 = w4[0], q1 = w4[1], q2 = w4[2], q3 = w4[3];
    float wv[16] = { q0.x, q0.y, q0.z, q0.w,
                     q1.x, q1.y, q1.z, q1.w,
                     q2.x, q2.y, q2.z, q2.w,
                     q3.x, q3.y, q3.z, q3.w };
    float m = -1e30f;
#pragma unroll
    for (int t = 0; t < 16; ++t) m = fmaxf(m, wv[t]);
    float s = 0.f;
#pragma unroll
    for (int t = 0; t < 16; ++t) { wv[t] = __expf(wv[t] - m); s += wv[t]; }
    float inv = 1.0f / s;

    float c0  = (wv[8] + wv[9] + wv[10] + wv[11] + wv[12] + wv[13] + wv[14] + wv[15]) * inv;
    float ca  = (wv[2] + wv[3] + wv[6] + wv[7] - wv[8] - wv[9] - wv[12] - wv[13]) * inv;
    float cb  = (wv[4] + wv[5] + wv[6] + wv[7] - wv[8] - wv[9] - wv[10] - wv[11]) * inv;
    float cab = (wv[1] - wv[2] - wv[4] - 2.f * wv[6] - wv[7]
               + wv[8] + 2.f * wv[9] + wv[11] + wv[13] - wv[14]) * inv;
    return make_float4(c0, ca, cb, cab);       // (c0, ca, cb, cab)
}

__global__ __launch_bounds__(TPB, 4) void logic_kernel(
    const float* __restrict__ x,
    const float* __restrict__ w,
    const int* __restrict__ idx_a,
    const int* __restrict__ idx_b,
    float* __restrict__ out)
{
    __shared__ float xrow[2][IN_DIM];        // 64 KB -> 2 blocks/CU (LDS-limited)

    const int tid  = threadIdx.x;
    const int row0 = blockIdx.x * RPB;

    // ---- 1. DMA row0 -> buf0 FIRST (overlaps the whole prologue) ----
    {
        const float* xr = x + (size_t)row0 * IN_DIM;
#pragma unroll
        for (int i = 0; i < NSTG; ++i)
            GLOAD_LDS16(xr + 4 * (i * TPB + tid), &xrow[0][4 * (i * TPB + tid)]);
    }
    MEMFENCE();

    // ---- 2. pack indices (WHOLE int4 assignments -> SROA-safe) ----
    int4 pi[NQ];
#pragma unroll
    for (int q = 0; q < NQ; ++q) {
        int j4 = q * TPB + tid;                       // quad of columns 4*j4..4*j4+3
        int4 ia = ((const int4*)idx_a)[j4];
        int4 ib = ((const int4*)idx_b)[j4];
        pi[q] = make_int4(((ia.x << 2) & 0xffff) | (ib.x << 18),
                          ((ia.y << 2) & 0xffff) | (ib.y << 18),
                          ((ia.z << 2) & 0xffff) | (ib.z << 18),
                          ((ia.w << 2) & 0xffff) | (ib.w << 18));
    }
    __builtin_amdgcn_sched_barrier(0);

    // ---- 3. coeffs: 2 columns at a time, WHOLE float4 assignments ----
    // cA[2q+h] = (c0,ca | c0,ca) for columns 4*j4+2h, +2h+1; cB likewise (cb,cab).
    float4 cA[2 * NQ];
    float4 cB[2 * NQ];
#pragma unroll
    for (int q = 0; q < NQ; ++q) {
#pragma unroll
        for (int h = 0; h < 2; ++h) {
            int j0 = 4 * (q * TPB + tid) + 2 * h;
            float4 e = softmax_coeffs(w, j0);          // (c0,ca,cb,cab) col even
            __builtin_amdgcn_sched_barrier(0);
            float4 o = softmax_coeffs(w, j0 + 1);      // col odd
            cA[2 * q + h] = make_float4(e.x, e.y, o.x, o.y);
            cB[2 * q + h] = make_float4(e.z, e.w, o.z, o.w);
            __builtin_amdgcn_sched_barrier(0);         // cap transient w-load pressure
        }
    }
    MEMFENCE();

#pragma unroll
    for (int r = 0; r < RPB; ++r) {
        // bar_A: every wave finished READING buf[(r+1)&1] (last read in iter r-1)
        __builtin_amdgcn_s_barrier();

        // issue next row's DMA BEFORE waiting on the current row's DMA
        if (r + 1 < RPB) {
            const float* xn = x + (size_t)(row0 + r + 1) * IN_DIM;
#pragma unroll
            for (int i = 0; i < NSTG; ++i)
                GLOAD_LDS16(xn + 4 * (i * TPB + tid), &xrow[(r + 1) & 1][4 * (i * TPB + tid)]);
        }
        MEMFENCE();

        // counted retire of DMA(r) only (never drain to 0 mid-loop)
        if (r == 0 || r + 1 == RPB) asm volatile("s_waitcnt vmcnt(4)" ::: "memory");
        else                        asm volatile("s_waitcnt vmcnt(8)" ::: "memory");
        __builtin_amdgcn_s_barrier();   // bar_B: LDS row r valid for all waves
        MEMFENCE();

        const char* xb = (const char*)xrow[r & 1];
        fvec4* out4 = (fvec4*)(out + (size_t)(row0 + r) * OUT_DIM);

#pragma unroll
        for (int q = 0; q < NQ; ++q) {
            int4 p = pi[q];
            // byte-offset gathers (pi holds idx*4 packed in 16-bit halves)
            float a0 = *(const float*)(xb + (p.x & 0xffff)), b0 = *(const float*)(xb + ((unsigned)p.x >> 16));
            float a1 = *(const float*)(xb + (p.y & 0xffff)), b1 = *(const float*)(xb + ((unsigned)p.y >> 16));
            float a2 = *(const float*)(xb + (p.z & 0xffff)), b2 = *(const float*)(xb + ((unsigned)p.z >> 16));
            float a3 = *(const float*)(xb + (p.w & 0xffff)), b3 = *(const float*)(xb + ((unsigned)p.w >> 16));

            float4 A0 = cA[2 * q], A1 = cA[2 * q + 1];
            float4 B0 = cB[2 * q], B1 = cB[2 * q + 1];

            // o = (c0 + ca*a) + b*(cb + cab*a)   -- 3 FMAs per output
            fvec4 o;
            o.x = fmaf(fmaf(B0.y, a0, B0.x), b0, fmaf(A0.y, a0, A0.x));
            o.y = fmaf(fmaf(B0.w, a1, B0.z), b1, fmaf(A0.w, a1, A0.z));
            o.z = fmaf(fmaf(B1.y, a2, B1.x), b2, fmaf(A1.y, a2, A1.x));
            o.w = fmaf(fmaf(B1.w, a3, B1.z), b3, fmaf(A1.w, a3, A1.z));
            __builtin_nontemporal_store(o, &out4[q * TPB + tid]);
        }
        MEMFENCE();
    }
}

extern "C" void kernel_launch(void* const* d_in, const int* in_sizes, int n_in,
                              void* d_out, int out_size, void* d_ws, size_t ws_size,
                              hipStream_t stream)
{
    const float* x       = (const float*)d_in[0];  // (2048, 8192) fp32
    const float* weights = (const float*)d_in[1];  // (8192, 16)   fp32
    const int*   idx_a   = (const int*)d_in[2];    // (8192,) int32 on device
    const int*   idx_b   = (const int*)d_in[3];    // (8192,) int32 on device
    float* out = (float*)d_out;                    // (2048, 8192) fp32

    logic_kernel<<<BATCH / RPB, TPB, 0, stream>>>(x, weights, idx_a, idx_b, out);
}

// Round 8
// 118.747 us; speedup vs baseline: 2.1895x; 2.1721x over previous
//
#include <hip/hip_runtime.h>
#include <hip/hip_fp16.h>

#define IN_DIM 8192
#define OUT_DIM 8192
#define BATCH 2048
#define TPB 512                      // 8 waves/block
#define RPB 4                        // rows per block; grid = 512 = 2 blocks/CU
#define NQ (OUT_DIM / 4 / TPB)       // 4 float4-output quads per thread per row
#define NSTG (IN_DIM / 4 / TPB)      // 4 direct-to-LDS 16B loads per thread per row

typedef float fvec4 __attribute__((ext_vector_type(4)));

#define GLOAD_LDS16(gp, lp)                                                        \
    __builtin_amdgcn_global_load_lds(                                              \
        (const __attribute__((address_space(1))) unsigned int*)(gp),               \
        (__attribute__((address_space(3))) unsigned int*)(lp), 16, 0, 0)

#define MEMFENCE() asm volatile("" ::: "memory")

// ---------------------------------------------------------------------------
// Kernel 1: softmax(16) -> 4 affine coeffs {1,a,b,ab} in FP32:
//   pidx[j] = (idx_a*4) | (idx_b*4 << 16)   -- BYTE offsets (idx<8192 -> *4 < 32768)
//   pcA[j]  = float2(c0, ca), pcB[j] = float2(cb, cab)
// ---------------------------------------------------------------------------
__global__ __launch_bounds__(64) void coeff_kernel(
    const float* __restrict__ w,
    const int* __restrict__ idx_a,
    const int* __restrict__ idx_b,
    int* __restrict__ pidx,
    float2* __restrict__ pcA,
    float2* __restrict__ pcB)
{
    int j = blockIdx.x * 64 + threadIdx.x;     // grid exact: 8192 = 128*64

    const float4* w4 = (const float4*)(w + (size_t)j * 16);
    float4 q0 = w4[0], q1 = w4[1], q2 = w4[2], q3 = w4[3];
    float wv[16] = { q0.x, q0.y, q0.z, q0.w,
                     q1.x, q1.y, q1.z, q1.w,
                     q2.x, q2.y, q2.z, q2.w,
                     q3.x, q3.y, q3.z, q3.w };

    float m = -1e30f;
#pragma unroll
    for (int k = 0; k < 16; ++k) m = fmaxf(m, wv[k]);
    float s = 0.f;
#pragma unroll
    for (int k = 0; k < 16; ++k) { wv[k] = __expf(wv[k] - m); s += wv[k]; }
    float inv = 1.0f / s;
#pragma unroll
    for (int k = 0; k < 16; ++k) wv[k] *= inv;

    float c0  = wv[8] + wv[9] + wv[10] + wv[11] + wv[12] + wv[13] + wv[14] + wv[15];
    float ca  = wv[2] + wv[3] + wv[6] + wv[7] - wv[8] - wv[9] - wv[12] - wv[13];
    float cb  = wv[4] + wv[5] + wv[6] + wv[7] - wv[8] - wv[9] - wv[10] - wv[11];
    float cab = wv[1] - wv[2] - wv[4] - 2.f * wv[6] - wv[7]
              + wv[8] + 2.f * wv[9] + wv[11] + wv[13] - wv[14];

    pidx[j] = ((idx_a[j] << 2) & 0xffff) | (idx_b[j] << 18);
    pcA[j]  = make_float2(c0, ca);
    pcB[j]  = make_float2(cb, cab);
}

// ---------------------------------------------------------------------------
// Kernel 2: 4 rows per block, coeffs register-resident (row-invariant),
// double-buffered LDS staging via global_load_lds with ISSUE-EARLY schedule:
//
//   iter r: bar_A (all waves finished reading buf[(r+1)&1] in iter r-1)
//           issue DMA(row r+1 -> buf[(r+1)&1])        <-- before the wait!
//           s_waitcnt vmcnt(8)  -- retires exactly DMA(r); st(r-1) and
//                                  DMA(r+1) stay in flight across bar_B
//           bar_B (LDS row r valid for all waves)
//           compute row r from buf[r&1], 4x nontemporal float4 stores
//
// Per-wave vmem FIFO at the vmcnt point: [DMA(r) x4 | st(r-1) x4 | DMA(r+1) x4]
//  -> vmcnt(8) is the counted wait. Edges: r==0 -> vmcnt(4) (drains the 20
// coeff loads too, which are older); r==RPB-1 -> vmcnt(4) (no DMA issued).
// ---------------------------------------------------------------------------
__global__ __launch_bounds__(TPB, 4) void logic_kernel(
    const float* __restrict__ x,
    const int* __restrict__ pidx,
    const float2* __restrict__ pcA,
    const float2* __restrict__ pcB,
    float* __restrict__ out)
{
    __shared__ float xrow[2][IN_DIM];        // 64 KB -> 2 blocks/CU (LDS-limited)

    const int tid  = threadIdx.x;
    const int row0 = blockIdx.x * RPB;

    // ---- coeffs ONCE into registers (reused for all 4 rows) ----
    const int4*   pidx4 = (const int4*)pidx;
    const float4* pA4   = (const float4*)pcA;
    const float4* pB4   = (const float4*)pcB;

    int4   pi[NQ];
    float4 cA[2 * NQ];
    float4 cB[2 * NQ];
#pragma unroll
    for (int q = 0; q < NQ; ++q) {
        int j4 = q * TPB + tid;
        pi[q]         = pidx4[j4];
        cA[2 * q]     = pA4[2 * j4];
        cA[2 * q + 1] = pA4[2 * j4 + 1];
        cB[2 * q]     = pB4[2 * j4];
        cB[2 * q + 1] = pB4[2 * j4 + 1];
    }
    MEMFENCE();   // coeff loads issued before DMA(0) -- keeps the FIFO math exact

    // ---- prologue: DMA row0 -> buf0 ----
    {
        const float* xr = x + (size_t)row0 * IN_DIM;
#pragma unroll
        for (int i = 0; i < NSTG; ++i)
            GLOAD_LDS16(xr + 4 * (i * TPB + tid), &xrow[0][4 * (i * TPB + tid)]);
    }
    MEMFENCE();

#pragma unroll
    for (int r = 0; r < RPB; ++r) {
        // bar_A: every wave is done READING buf[(r+1)&1] (last read in iter r-1)
        __builtin_amdgcn_s_barrier();

        // issue next row's DMA BEFORE waiting on the current row's DMA
        if (r + 1 < RPB) {
            const float* xn = x + (size_t)(row0 + r + 1) * IN_DIM;
#pragma unroll
            for (int i = 0; i < NSTG; ++i)
                GLOAD_LDS16(xn + 4 * (i * TPB + tid), &xrow[(r + 1) & 1][4 * (i * TPB + tid)]);
        }
        MEMFENCE();

        // counted retire of DMA(r) only (never drain to 0 mid-loop)
        if (r == 0 || r + 1 == RPB) asm volatile("s_waitcnt vmcnt(4)" ::: "memory");
        else                        asm volatile("s_waitcnt vmcnt(8)" ::: "memory");
        __builtin_amdgcn_s_barrier();   // bar_B: LDS row r valid for all waves
        MEMFENCE();

        const char* xb = (const char*)xrow[r & 1];
        fvec4* out4 = (fvec4*)(out + (size_t)(row0 + r) * OUT_DIM);

#pragma unroll
        for (int q = 0; q < NQ; ++q) {
            int4 p = pi[q];
            // byte-offset gathers (pidx holds idx*4 packed in 16-bit halves)
            float a0 = *(const float*)(xb + (p.x & 0xffff)), b0 = *(const float*)(xb + ((unsigned)p.x >> 16));
            float a1 = *(const float*)(xb + (p.y & 0xffff)), b1 = *(const float*)(xb + ((unsigned)p.y >> 16));
            float a2 = *(const float*)(xb + (p.z & 0xffff)), b2 = *(const float*)(xb + ((unsigned)p.z >> 16));
            float a3 = *(const float*)(xb + (p.w & 0xffff)), b3 = *(const float*)(xb + ((unsigned)p.w >> 16));

            float4 A0 = cA[2 * q], A1 = cA[2 * q + 1];
            float4 B0 = cB[2 * q], B1 = cB[2 * q + 1];

            // o = (c0 + ca*a) + b*(cb + cab*a)   -- 3 FMAs per output
            fvec4 o;
            o.x = fmaf(fmaf(B0.y, a0, B0.x), b0, fmaf(A0.y, a0, A0.x));
            o.y = fmaf(fmaf(B0.w, a1, B0.z), b1, fmaf(A0.w, a1, A0.z));
            o.z = fmaf(fmaf(B1.y, a2, B1.x), b2, fmaf(A1.y, a2, A1.x));
            o.w = fmaf(fmaf(B1.w, a3, B1.z), b3, fmaf(A1.w, a3, A1.z));
            __builtin_nontemporal_store(o, &out4[q * TPB + tid]);
        }
        MEMFENCE();
    }
}

extern "C" void kernel_launch(void* const* d_in, const int* in_sizes, int n_in,
                              void* d_out, int out_size, void* d_ws, size_t ws_size,
                              hipStream_t stream)
{
    const float* x       = (const float*)d_in[0];  // (2048, 8192) fp32
    const float* weights = (const float*)d_in[1];  // (8192, 16)   fp32
    const int*   idx_a   = (const int*)d_in[2];    // (8192,) int32 on device
    const int*   idx_b   = (const int*)d_in[3];    // (8192,) int32 on device
    float* out = (float*)d_out;                    // (2048, 8192) fp32

    int*    pidx = (int*)d_ws;                     // 32 KB
    float2* pcA  = (float2*)(pidx + OUT_DIM);      // 64 KB
    float2* pcB  = pcA + OUT_DIM;                  // 64 KB

    coeff_kernel<<<OUT_DIM / 64, 64, 0, stream>>>(weights, idx_a, idx_b, pidx, pcA, pcB);
    logic_kernel<<<BATCH / RPB, TPB, 0, stream>>>(x, pidx, pcA, pcB, out);
}